// Round 8
// baseline (427.030 us; speedup 1.0000x reference)
//
#include <hip/hip_runtime.h>

#define D 128
#define NBSHIFT 10          // 1024 nodes per bucket
#define NB (1 << NBSHIFT)
#define EPB 2048            // edges per bucketing block

typedef __attribute__((ext_vector_type(8))) short bf16x8;
typedef __attribute__((ext_vector_type(4))) float floatx4;

__device__ __forceinline__ float bflo(unsigned int u){ return __uint_as_float(u << 16); }
__device__ __forceinline__ float bfhi(unsigned int u){ return __uint_as_float(u & 0xffff0000u); }
__device__ __forceinline__ unsigned int f2bfbits(float f){
    unsigned int x = __float_as_uint(f);
    return (x + 0x7fffu + ((x >> 16) & 1u)) >> 16;  // RNE, finite inputs
}

// ---- per-block bucket histograms (no global atomics) ----
__global__ __launch_bounds__(256) void k_bcount(const int* __restrict__ dst,
                                                int* __restrict__ hist, int E){
    __shared__ int h[128];
    int t = threadIdx.x;
    int base = blockIdx.x * EPB;
    if (t < 128) h[t] = 0;
    __syncthreads();
#pragma unroll
    for (int j = 0; j < 8; ++j){
        int e = base + j * 256 + t;
        if (e < E) atomicAdd(&h[dst[e] >> NBSHIFT], 1);
    }
    __syncthreads();
    if (t < 128) hist[blockIdx.x * 128 + t] = h[t];
}

// ---- column-scan of hists: per-(block,bucket) exclusive offsets + bucket bases ----
// 1 block, 128 threads (thread = bucket). Reads/writes coalesced 512 B per iter.
__global__ __launch_bounds__(128) void k_colscan(const int* __restrict__ hist, int nH,
                                                 int* __restrict__ gloc, int* __restrict__ bbase,
                                                 int* __restrict__ rowStartN){
    int b = threadIdx.x;
    int run = 0;
    int blk = 0;
    for (; blk + 4 <= nH; blk += 4){
        int v0 = hist[(blk + 0) * 128 + b];
        int v1 = hist[(blk + 1) * 128 + b];
        int v2 = hist[(blk + 2) * 128 + b];
        int v3 = hist[(blk + 3) * 128 + b];
        gloc[(blk + 0) * 128 + b] = run;
        gloc[(blk + 1) * 128 + b] = run + v0;
        gloc[(blk + 2) * 128 + b] = run + v0 + v1;
        gloc[(blk + 3) * 128 + b] = run + v0 + v1 + v2;
        run += v0 + v1 + v2 + v3;
    }
    for (; blk < nH; ++blk){
        int v = hist[blk * 128 + b];
        gloc[blk * 128 + b] = run;
        run += v;
    }
    __shared__ int sm[128];
    sm[b] = run; __syncthreads();
    for (int off = 1; off < 128; off <<= 1){
        int x = (b >= off) ? sm[b - off] : 0;
        __syncthreads();
        sm[b] += x;
        __syncthreads();
    }
    bbase[b] = (b > 0) ? sm[b - 1] : 0;
    if (b == 127){ bbase[128] = sm[127]; *rowStartN = sm[127]; }
}

// ---- pass 1: partition edges into dst-buckets (zero global atomics) ----
// pack = src | (dstLow << 20)   (requires N < 2^20)
__global__ __launch_bounds__(256) void k_bucket(const int* __restrict__ src, const int* __restrict__ dst,
                                                const int* __restrict__ hist, const int* __restrict__ gloc,
                                                const int* __restrict__ bbase,
                                                unsigned int* __restrict__ edge1, int E){
    __shared__ int sc[128], lstart[128], lcur[128], gb[128];
    __shared__ unsigned int stage[EPB];
    int t = threadIdx.x, blk = blockIdx.x;
    int base = blk * EPB;
    int tot = min(EPB, E - base);
    int hv = 0;
    if (t < 128){ hv = hist[blk * 128 + t]; sc[t] = hv; }
    __syncthreads();
    for (int off = 1; off < 128; off <<= 1){
        int v = (t < 128 && t >= off) ? sc[t - off] : 0;
        __syncthreads();
        if (t < 128) sc[t] += v;
        __syncthreads();
    }
    if (t < 128){
        int ex = sc[t] - hv;
        lstart[t] = ex; lcur[t] = ex;
        gb[t] = bbase[t] + gloc[blk * 128 + t];
    }
    __syncthreads();
#pragma unroll
    for (int j = 0; j < 8; ++j){
        int e = base + j * 256 + t;
        if (e < E){
            unsigned s = (unsigned)src[e], d = (unsigned)dst[e];
            int bk = (int)(d >> NBSHIFT);
            int pos = atomicAdd(&lcur[bk], 1);   // LDS atomic only
            stage[pos] = s | ((d & (NB - 1)) << 20);
        }
    }
    __syncthreads();
    for (int i = t; i < tot; i += 256){
        unsigned int e1 = stage[i];
        int lo = 0, hi = 127;
        while (lo < hi){
            int m = (lo + hi + 1) >> 1;
            if (lstart[m] <= i) lo = m; else hi = m - 1;
        }
        edge1[gb[lo] + (i - lstart[lo])] = e1;
    }
}

// ---- pass 2: per-bucket degree hist + scan + CSR scatter (all LDS) ----
__global__ __launch_bounds__(1024) void k_csr2(const unsigned int* __restrict__ edge1,
                                               const int* __restrict__ bbase,
                                               int* __restrict__ rowStart, float* __restrict__ dinv,
                                               int* __restrict__ csr, int N){
    __shared__ int hist[NB];
    __shared__ int sc[NB];
    int b = blockIdx.x, t = threadIdx.x;
    int nbase = b << NBSHIFT;
    int nn = min(N - nbase, NB);
    int ebeg = bbase[b], eend = bbase[b + 1];

    if (t < NB) hist[t] = 0;
    __syncthreads();
    for (int i = ebeg + t; i < eend; i += 1024)
        atomicAdd(&hist[edge1[i] >> 20], 1);
    __syncthreads();
    if (t < NB) sc[t] = hist[t];
    __syncthreads();
    for (int off = 1; off < NB; off <<= 1){
        int v = (t >= off && t < NB) ? sc[t - off] : 0;
        __syncthreads();
        if (t < NB) sc[t] += v;
        __syncthreads();
    }
    if (t < NB){
        int cur = ebeg + sc[t] - hist[t];
        sc[t] = cur;
        if (t < nn){
            rowStart[nbase + t] = cur;
            dinv[nbase + t] = rsqrtf((float)hist[t] + 1.0f);  // +1 self-loop
        }
    }
    __syncthreads();
    for (int i = ebeg + t; i < eend; i += 1024){
        unsigned int p = edge1[i];
        int pos = atomicAdd(&sc[p >> 20], 1);
        csr[pos] = (int)(p & 0xFFFFFu);
    }
}

// ---- transpose + fp32->bf16 weights ----
__global__ __launch_bounds__(256) void k_wtrans(const float* __restrict__ W1,
                                                const float* __restrict__ W2,
                                                unsigned short* __restrict__ Wt1,
                                                unsigned short* __restrict__ Wt2){
    int i = blockIdx.x * 256 + threadIdx.x;
    const float* Ws; unsigned short* Wd; int j = i;
    if (i < 16384){ Ws = W1; Wd = Wt1; } else { Ws = W2; Wd = Wt2; j -= 16384; }
    int k = j >> 7, n = j & 127;
    Wd[n * 128 + k] = (unsigned short)f2bfbits(Ws[k * 128 + n]);
}

// ---- bf16 MFMA GEMM, swapped operands: A = Wt rows (channels), B = x rows (nodes) ----
// D[ch][node]: col=lane&15 -> node, row=quad*4+r -> channel. Lane owns 4 contiguous
// channels per nt tile -> vectorized epilogue via swizzled LDS bounce.
template<bool A_BF16>
__global__ __launch_bounds__(256) void k_gemm(const void* __restrict__ Av,
                                              const unsigned short* __restrict__ Wt,
                                              unsigned short* __restrict__ Hout, int Nrows){
    __shared__ __align__(16) unsigned short tile[4][2048];  // 4 waves x 16x128 bf16
    int wave = threadIdx.x >> 6, lane = threadIdx.x & 63;
    int j = lane & 15, quad = lane >> 4;     // j = node (B free index) = A's m reuse
    int row0 = blockIdx.x * 64 + wave * 16;
    int arow = row0 + j;
    int arowc = arow < Nrows ? arow : Nrows - 1;

    // B fragment: B[k=quad*8+idx][n=j] = x[row0+j][k]
    bf16x8 bx[4];
    if (A_BF16){
        const unsigned short* Ap = (const unsigned short*)Av + (size_t)arowc * D + quad * 8;
#pragma unroll
        for (int kt = 0; kt < 4; ++kt) bx[kt] = *(const bf16x8*)(Ap + kt * 32);
    } else {
        const float* Ap = (const float*)Av + (size_t)arowc * D + quad * 8;
#pragma unroll
        for (int kt = 0; kt < 4; ++kt){
            float4 v0 = *(const float4*)(Ap + kt * 32);
            float4 v1 = *(const float4*)(Ap + kt * 32 + 4);
            bf16x8 af;
            af[0] = (short)f2bfbits(v0.x); af[1] = (short)f2bfbits(v0.y);
            af[2] = (short)f2bfbits(v0.z); af[3] = (short)f2bfbits(v0.w);
            af[4] = (short)f2bfbits(v1.x); af[5] = (short)f2bfbits(v1.y);
            af[6] = (short)f2bfbits(v1.z); af[7] = (short)f2bfbits(v1.w);
            bx[kt] = af;
        }
    }

    floatx4 acc[8];
#pragma unroll
    for (int nt = 0; nt < 8; ++nt) acc[nt] = (floatx4){0.f, 0.f, 0.f, 0.f};

    // A fragment: A[m=lane&15][k=quad*8+idx] = Wt[nt*16 + m][k]
    const unsigned short* Wp = Wt + j * D + quad * 8;
#pragma unroll
    for (int kt = 0; kt < 4; ++kt){
#pragma unroll
        for (int nt = 0; nt < 8; ++nt){
            bf16x8 aw = *(const bf16x8*)(Wp + nt * 16 * D + kt * 32);
            acc[nt] = __builtin_amdgcn_mfma_f32_16x16x32_bf16(aw, bx[kt], acc[nt], 0, 0, 0);
        }
    }

    // epilogue: acc[nt][r] = h[row0 + j][nt*16 + quad*4 + r]
    unsigned short* tw = tile[wave];
#pragma unroll
    for (int nt = 0; nt < 8; ++nt){
        unsigned lo = f2bfbits(acc[nt][0]) | (f2bfbits(acc[nt][1]) << 16);
        unsigned hi = f2bfbits(acc[nt][2]) | (f2bfbits(acc[nt][3]) << 16);
        int waddr = j * 256 + nt * 32 + quad * 8;
        waddr ^= (j & 7) * 32;               // bank swizzle
        *(uint2*)((char*)tw + waddr) = make_uint2(lo, hi);
    }
    int remb = (Nrows - row0) * 256;         // valid bytes of this tile
    char* gout = (char*)Hout + (size_t)row0 * 256;
#pragma unroll
    for (int it = 0; it < 4; ++it){
        int off = it * 1024 + lane * 16;
        int jr = off >> 8;
        int raddr = off ^ ((jr & 7) * 32);
        uint4 v = *(const uint4*)((const char*)tw + raddr);
        if (off < remb) *(uint4*)(gout + off) = v;
    }
}

// ---- fused gather-aggregate + bias + LayerNorm + ReLU ----
template<bool OUT_BF16>
__global__ __launch_bounds__(256) void k_agg(const unsigned short* __restrict__ h,
                                             const int* __restrict__ rowStart,
                                             const int* __restrict__ csr,
                                             const float* __restrict__ dinv,
                                             const float* __restrict__ bias,
                                             const float* __restrict__ gamma,
                                             const float* __restrict__ beta,
                                             void* __restrict__ outv, int N){
    int node = blockIdx.x * 4 + (threadIdx.x >> 6);
    if (node >= N) return;
    int lane = threadIdx.x & 63;
    int half = lane >> 5, li = lane & 31;   // lane owns channels 4*li..4*li+3
    const uint2* hv = (const uint2*)h;

    float dv = dinv[node];
    float4 acc = {0.f, 0.f, 0.f, 0.f};
    if (half == 0){
        uint2 hs = hv[(size_t)node * 32 + li];
        float w0 = dv * dv;
        acc.x = bflo(hs.x) * w0; acc.y = bfhi(hs.x) * w0;
        acc.z = bflo(hs.y) * w0; acc.w = bfhi(hs.y) * w0;
    }

    int start = rowStart[node], end = rowStart[node + 1];
    int mid = start + ((end - start + 1) >> 1);
    int i    = half ? mid : start;
    int iend = half ? end : mid;

    for (; i + 4 <= iend; i += 4){
        int s0 = csr[i], s1 = csr[i + 1], s2 = csr[i + 2], s3 = csr[i + 3];
        uint2 h0 = hv[(size_t)s0 * 32 + li];
        uint2 h1 = hv[(size_t)s1 * 32 + li];
        uint2 h2 = hv[(size_t)s2 * 32 + li];
        uint2 h3 = hv[(size_t)s3 * 32 + li];
        float w0 = dinv[s0] * dv, w1 = dinv[s1] * dv, w2 = dinv[s2] * dv, w3 = dinv[s3] * dv;
        acc.x = fmaf(bflo(h0.x), w0, acc.x); acc.y = fmaf(bfhi(h0.x), w0, acc.y);
        acc.z = fmaf(bflo(h0.y), w0, acc.z); acc.w = fmaf(bfhi(h0.y), w0, acc.w);
        acc.x = fmaf(bflo(h1.x), w1, acc.x); acc.y = fmaf(bfhi(h1.x), w1, acc.y);
        acc.z = fmaf(bflo(h1.y), w1, acc.z); acc.w = fmaf(bfhi(h1.y), w1, acc.w);
        acc.x = fmaf(bflo(h2.x), w2, acc.x); acc.y = fmaf(bfhi(h2.x), w2, acc.y);
        acc.z = fmaf(bflo(h2.y), w2, acc.z); acc.w = fmaf(bfhi(h2.y), w2, acc.w);
        acc.x = fmaf(bflo(h3.x), w3, acc.x); acc.y = fmaf(bfhi(h3.x), w3, acc.y);
        acc.z = fmaf(bflo(h3.y), w3, acc.z); acc.w = fmaf(bfhi(h3.y), w3, acc.w);
    }
    for (; i < iend; ++i){
        int s = csr[i];
        float ws = dinv[s] * dv;
        uint2 hs = hv[(size_t)s * 32 + li];
        acc.x = fmaf(bflo(hs.x), ws, acc.x); acc.y = fmaf(bfhi(hs.x), ws, acc.y);
        acc.z = fmaf(bflo(hs.y), ws, acc.z); acc.w = fmaf(bfhi(hs.y), ws, acc.w);
    }

    acc.x += __shfl_xor(acc.x, 32, 64);
    acc.y += __shfl_xor(acc.y, 32, 64);
    acc.z += __shfl_xor(acc.z, 32, 64);
    acc.w += __shfl_xor(acc.w, 32, 64);

    float4 bb = ((const float4*)bias)[li];
    acc.x += bb.x; acc.y += bb.y; acc.z += bb.z; acc.w += bb.w;

    float s1 = acc.x + acc.y + acc.z + acc.w;
    float s2 = acc.x * acc.x + acc.y * acc.y + acc.z * acc.z + acc.w * acc.w;
#pragma unroll
    for (int off = 16; off > 0; off >>= 1){
        s1 += __shfl_xor(s1, off, 64);
        s2 += __shfl_xor(s2, off, 64);
    }
    float mu = s1 * (1.0f / 128.0f);
    float var = s2 * (1.0f / 128.0f) - mu * mu;
    float rstd = rsqrtf(var + 1e-5f);

    float4 gg = ((const float4*)gamma)[li];
    float4 be = ((const float4*)beta)[li];
    float ox = fmaxf(fmaf((acc.x - mu) * rstd, gg.x, be.x), 0.0f);
    float oy = fmaxf(fmaf((acc.y - mu) * rstd, gg.y, be.y), 0.0f);
    float oz = fmaxf(fmaf((acc.z - mu) * rstd, gg.z, be.z), 0.0f);
    float ow = fmaxf(fmaf((acc.w - mu) * rstd, gg.w, be.w), 0.0f);
    if (half == 0){
        if (OUT_BF16){
            uint2 o;
            o.x = f2bfbits(ox) | (f2bfbits(oy) << 16);
            o.y = f2bfbits(oz) | (f2bfbits(ow) << 16);
            ((uint2*)outv)[(size_t)node * 32 + li] = o;
        } else {
            floatx4 o = {ox, oy, oz, ow};
            __builtin_nontemporal_store(o, (floatx4*)outv + (size_t)node * 32 + li);
        }
    }
}

extern "C" void kernel_launch(void* const* d_in, const int* in_sizes, int n_in,
                              void* d_out, int out_size, void* d_ws, size_t ws_size,
                              hipStream_t stream){
    const float* x   = (const float*)d_in[0];
    const int*   ei  = (const int*)d_in[1];
    const float* W1  = (const float*)d_in[2];
    const float* b1  = (const float*)d_in[3];
    const float* g1  = (const float*)d_in[4];
    const float* be1 = (const float*)d_in[5];
    const float* W2  = (const float*)d_in[6];
    const float* b2  = (const float*)d_in[7];
    const float* g2  = (const float*)d_in[8];
    const float* be2 = (const float*)d_in[9];
    float* out = (float*)d_out;

    const int N = in_sizes[0] / D;
    const int E = in_sizes[1] / 2;
    const int* src = ei;
    const int* dst = ei + E;

    char* w = (char*)d_ws;
    size_t off = 0;
    auto alloc = [&](size_t bytes) -> char* {
        char* p = w + off;
        off = (off + bytes + 255) & ~(size_t)255;
        return p;
    };
    const int NBK = (N + NB - 1) >> NBSHIFT;
    const int nH  = (E + EPB - 1) / EPB;
    int*            hist     = (int*)alloc((size_t)nH * 128 * 4);
    int*            gloc     = (int*)alloc((size_t)nH * 128 * 4);
    int*            bbase    = (int*)alloc(129 * 4);
    int*            rowStart = (int*)alloc((size_t)(N + 1) * 4);
    float*          dinv     = (float*)alloc((size_t)N * 4);
    unsigned int*   edge1    = (unsigned int*)alloc((size_t)E * 4);
    int*            csr      = (int*)alloc((size_t)E * 4);
    unsigned short* wt1      = (unsigned short*)alloc(16384 * 2);
    unsigned short* wt2      = (unsigned short*)alloc(16384 * 2);
    unsigned short* h        = (unsigned short*)alloc((size_t)N * D * 2);
    unsigned short* hmid     = (unsigned short*)d_out;  // bf16 mid activation in d_out

    int gG = (N + 63) / 64;
    int gA = (N + 3) / 4;

    k_bcount <<<nH, 256, 0, stream>>>(dst, hist, E);
    k_colscan<<<1, 128, 0, stream>>>(hist, nH, gloc, bbase, rowStart + N);
    k_bucket <<<nH, 256, 0, stream>>>(src, dst, hist, gloc, bbase, edge1, E);
    k_csr2   <<<NBK, 1024, 0, stream>>>(edge1, bbase, rowStart, dinv, csr, N);
    k_wtrans <<<128, 256, 0, stream>>>(W1, W2, wt1, wt2);

    // layer 1: gemm(x) -> h ; agg -> hmid (bf16, in d_out)
    k_gemm<false><<<gG, 256, 0, stream>>>(x, wt1, h, N);
    k_agg<true>  <<<gA, 256, 0, stream>>>(h, rowStart, csr, dinv, b1, g1, be1, hmid, N);
    // layer 2: gemm(hmid) -> h ; agg -> out (fp32, nontemporal)
    k_gemm<true> <<<gG, 256, 0, stream>>>(hmid, wt2, h, N);
    k_agg<false> <<<gA, 256, 0, stream>>>(h, rowStart, csr, dinv, b2, g2, be2, out, N);
}